// Round 22
// baseline (487.256 us; speedup 1.0000x reference)
//
#include <hip/hip_runtime.h>
#include <hip/hip_fp16.h>
#include <math.h>

// Problem constants (from reference)
#define N_NODES 50000
#define IN_DIM  128
#define HIDDEN  64
#define OUT_DIM 10
#define HEADS   4
#define E_RAW   800000
#define E_TOT   (E_RAW + N_NODES)   // with self-loops: 850000
#define NEG_SLOPE 0.2f

#define NB_SCAN 196    // ceil(50000/256)
#define NB_EDGE 3321   // ceil(850000/256)
#define NB_GEMH 782    // ceil(50000/64)
#define NB_NODE 12500  // 50000/4 (one wave per node)
#define NB_AL   1563   // ceil(50000/32) -- 32 nodes/block (8 lanes/node)

typedef _Float16 half8 __attribute__((ext_vector_type(8)));
typedef float floatx4 __attribute__((ext_vector_type(4)));

// ---------------- Fused prep: zero counts | detect dtype | Wtf | Wa --------
__global__ void prep_kernel(const int* __restrict__ ei, int* __restrict__ counts,
                            int* __restrict__ flag,
                            const float* __restrict__ W0, const float* __restrict__ W1,
                            const float* __restrict__ W2,
                            __half* __restrict__ Wtf0, __half* __restrict__ Wtf1,
                            __half* __restrict__ Wtf2,
                            const float* __restrict__ as0, const float* __restrict__ ad0,
                            const float* __restrict__ as1, const float* __restrict__ ad1,
                            const float* __restrict__ as2, const float* __restrict__ ad2,
                            float* __restrict__ Wa0, float* __restrict__ Wa1,
                            float* __restrict__ Wa2) {
    int bid = blockIdx.x, t = threadIdx.x;
    if (bid < 196) {                       // zero counts
        int i = bid * 256 + t;
        if (i < N_NODES) counts[i] = 0;
    } else if (bid == 196) {               // dtype detect: flag=1 -> int32
        __shared__ int anyv;
        if (t == 0) anyv = 0;
        __syncthreads();
        int idx = 2 * (t * 3100 + 17) + 1; // odd word, < 1.6M
        if (ei[idx] != 0) atomicOr(&anyv, 1);
        __syncthreads();
        if (t == 0) flag[0] = anyv;        // plain store: no pre-zero needed
    } else if (bid < 229) {                // Wtf fragments (MFMA B order)
        int i = (bid - 197) * 256 + t;
        int K, f;
        const float* W; __half* Wtf;
        if (i < 4096)      { f = i;        K = 128; W = W0; Wtf = Wtf0; }
        else if (i < 6144) { f = i - 4096; K = 64;  W = W1; Wtf = Wtf1; }
        else if (i < 8192) { f = i - 6144; K = 64;  W = W2; Wtf = Wtf2; }
        else return;
        int KC = K / 32;
        int lane = f & 63, kc = (f >> 6) % KC, ct = f / (64 * KC);
        int m = lane & 15, quad = lane >> 4;
        int col = ct * 16 + m;
        __half tmp[8];
#pragma unroll
        for (int j = 0; j < 8; j++)
            tmp[j] = __float2half(W[(kc * 32 + quad * 8 + j) * 256 + col]);
        *(uint4*)(Wtf + (size_t)f * 8) = *(uint4*)tmp;
    } else {                               // Wa: one block per (layer,k)
        int b = bid - 229;                 // 0..255
        int l, k;
        if (b < 128)      { l = 0; k = b; }
        else if (b < 192) { l = 1; k = b - 128; }
        else              { l = 2; k = b - 192; }
        const float* W  = (l == 0) ? W0 : (l == 1) ? W1 : W2;
        const float* as = (l == 0) ? as0 : (l == 1) ? as1 : as2;
        const float* ad = (l == 0) ? ad0 : (l == 1) ? ad1 : ad2;
        float* Wa       = (l == 0) ? Wa0 : (l == 1) ? Wa1 : Wa2;
        int h = t >> 6, d = t & 63;
        float wv = W[k * 256 + h * 64 + d];
        float ss = wv * as[h * 64 + d];
        float dd = wv * ad[h * 64 + d];
#pragma unroll
        for (int o = 1; o < 64; o <<= 1) {
            ss += __shfl_xor(ss, o, 64);
            dd += __shfl_xor(dd, o, 64);
        }
        if (d == 0) {
            Wa[k * 8 + h]     = ss;
            Wa[k * 8 + 4 + h] = dd;
        }
    }
}

// ---------------- Device bodies (shared by merged kernels) ----------------

// cast_al body, 8-lanes-per-node (r22): all 8 j-lanes of a node read the
// SAME X float4 (HW broadcast-merge: 8 rows x 16 B per instr — coalesced,
// vs r20-21 thread-per-node where each instr touched 64 lines and
// count_cast ran at VALU 1.4% / 0.78 TB/s). Lane owns complete AL[n,j]:
// ZERO cross-lane ops. AL stores: 64 consecutive floats/wave.
__device__ __forceinline__ void cast_al_body(
    int nbase, const float* __restrict__ X, const float* __restrict__ Wa,
    __half* __restrict__ Xh, float* __restrict__ AL) {
    int lane = threadIdx.x & 63;
    int ns = lane >> 3, j = lane & 7;     // node-sub, owned column
    int n = nbase + ns;
    if (n >= N_NODES) return;
    const float4* X4 = (const float4*)(X + (size_t)n * 128);
    float s = 0.f;
#pragma unroll 8
    for (int k4 = 0; k4 < 32; k4++) {
        float4 v = X4[k4];
        s += v.x * Wa[(k4 * 4 + 0) * 8 + j] + v.y * Wa[(k4 * 4 + 1) * 8 + j]
           + v.z * Wa[(k4 * 4 + 2) * 8 + j] + v.w * Wa[(k4 * 4 + 3) * 8 + j];
    }
    AL[n * 8 + j] = s;
    // cast: lane j converts its 16-float slice (L1 re-reads of hot lines)
#pragma unroll
    for (int c = 0; c < 2; c++) {
        float4 va = X4[j * 4 + c * 2], vb = X4[j * 4 + c * 2 + 1];
        __half2 hh[4] = {__float22half2_rn(make_float2(va.x, va.y)),
                         __float22half2_rn(make_float2(va.z, va.w)),
                         __float22half2_rn(make_float2(vb.x, vb.y)),
                         __float22half2_rn(make_float2(vb.z, vb.w))};
        *(uint4*)(Xh + (size_t)n * 128 + j * 16 + c * 8) = *(uint4*)hh;
    }
}

// al_gemm64 body, 8-lanes-per-node (K=64): same scheme, no cast.
__device__ __forceinline__ void al64_body(
    int nbase, const float* __restrict__ X, const float* __restrict__ Wa,
    float* __restrict__ AL) {
    int lane = threadIdx.x & 63;
    int ns = lane >> 3, j = lane & 7;
    int n = nbase + ns;
    if (n >= N_NODES) return;
    const float4* X4 = (const float4*)(X + (size_t)n * 64);
    float s = 0.f;
#pragma unroll 8
    for (int k4 = 0; k4 < 16; k4++) {
        float4 v = X4[k4];
        s += v.x * Wa[(k4 * 4 + 0) * 8 + j] + v.y * Wa[(k4 * 4 + 1) * 8 + j]
           + v.z * Wa[(k4 * 4 + 2) * 8 + j] + v.w * Wa[(k4 * 4 + 3) * 8 + j];
    }
    AL[n * 8 + j] = s;
}

// edge_weights body: EW[p] = exp(leaky(AL_src + AL_dst)) — no max shift
// (logits analytically bounded, validated rounds 4-21; exact-f32 logit path)
__device__ __forceinline__ void ew_body(
    int p, const float* __restrict__ AL, const int* __restrict__ esrc,
    const int* __restrict__ edst, float4* __restrict__ EW) {
    if (p >= E_TOT) return;
    int s = esrc[p], d = edst[p];
    const float4* AL4 = (const float4*)AL;
    float4 as = AL4[s * 2];
    float4 ad = AL4[d * 2 + 1];
    float v0 = as.x + ad.x; v0 = fmaxf(v0, NEG_SLOPE * v0);
    float v1 = as.y + ad.y; v1 = fmaxf(v1, NEG_SLOPE * v1);
    float v2 = as.z + ad.z; v2 = fmaxf(v2, NEG_SLOPE * v2);
    float v3 = as.w + ad.w; v3 = fmaxf(v3, NEG_SLOPE * v3);
    EW[p] = make_float4(__expf(v0), __expf(v1), __expf(v2), __expf(v3));
}

// gemm_h body (r18/r20 version — MFMA math verified, bank-padded epilogue)
template <int K>
__device__ __forceinline__ void gemm_h_body(
    int bid, _Float16* lds, const __half* __restrict__ Xh,
    const __half* __restrict__ Wtf, __half* __restrict__ H) {
    const int KC = K / 32;
    const int CTC = (K == 128) ? 8 : 16;
    const int NCHUNK = 16 / CTC;
    int t = threadIdx.x;
    int w = t >> 6, lane = t & 63;
    int m = lane & 15, quad = lane >> 4;
    int n0 = bid * 64;
    int nr = n0 + w * 16 + m;
    int nc = (nr < N_NODES) ? nr : (N_NODES - 1);

    half8 afrag[KC];
#pragma unroll
    for (int kc = 0; kc < KC; kc++)
        afrag[kc] = *(const half8*)(Xh + (size_t)nc * K + kc * 32 + quad * 8);

    floatx4 accs[16];
    const uint4* Wg = (const uint4*)Wtf;
#pragma unroll
    for (int c = 0; c < NCHUNK; c++) {
        __syncthreads();
        uint4* dstl = (uint4*)lds;
        const uint4* srcg = Wg + (size_t)c * 2048;
#pragma unroll
        for (int q = 0; q < 8; q++) dstl[t + 256 * q] = srcg[t + 256 * q];
        __syncthreads();
#pragma unroll
        for (int ctl = 0; ctl < CTC; ctl++) {
            floatx4 acc = {0.f, 0.f, 0.f, 0.f};
#pragma unroll
            for (int kc = 0; kc < KC; kc++) {
                half8 b = *(const half8*)&lds[((ctl * KC + kc) * 64 + lane) * 8];
                acc = __builtin_amdgcn_mfma_f32_16x16x32_f16(afrag[kc], b, acc, 0, 0, 0);
            }
            accs[c * CTC + ctl] = acc;
        }
    }
    __syncthreads();
    _Float16* myl = lds + w * (16 * 264);
#pragma unroll
    for (int ct = 0; ct < 16; ct++) {
        int cc = ct * 16 + m;            // GEMM col = h*64 + d
        int h = cc >> 6, d = cc & 63;
        int pos = d * 4 + h;             // H dim-major position
        int q = pos >> 6, o = pos & 63;  // padded quarter q at q*66
#pragma unroll
        for (int i = 0; i < 4; i++)
            myl[(quad * 4 + i) * 264 + q * 66 + o] = (_Float16)accs[ct][i];
    }
    __syncthreads();
    int r = t >> 2, p = t & 3;
    int n2 = n0 + r;
    if (n2 < N_NODES) {
        const _Float16* src = lds + (r >> 4) * (16 * 264) + (r & 15) * 264 + p * 66;
        uint4* dst = (uint4*)(H + (size_t)n2 * 256 + p * 64);
#pragma unroll
        for (int j = 0; j < 8; j++) dst[j] = ((const uint4*)src)[j];
    }
}

// ---------------- CSR build ----------------

// Merged: count_edges (blocks 0..NB_EDGE-1) + cast_al (rest). Independent:
// both depend only on prep.
__global__ void __launch_bounds__(256) count_cast(
    const int* __restrict__ ei, int* __restrict__ counts,
    const int* __restrict__ flag, const float* __restrict__ X,
    const float* __restrict__ Wa0, __half* __restrict__ Xh,
    float* __restrict__ AL) {
    if (blockIdx.x < NB_EDGE) {
        int t = blockIdx.x * 256 + threadIdx.x;
        if (t >= E_TOT) return;
        int sh = flag[0] ? 0 : 1;             // int32 -> 0, int64 -> 1
        int dst = (t < E_RAW) ? ei[(E_RAW + t) << sh] : (t - E_RAW);
        atomicAdd(&counts[dst], 1);
    } else {
        int nbase = (blockIdx.x - NB_EDGE) * 32 + (threadIdx.x >> 6) * 8;
        cast_al_body(nbase, X, Wa0, Xh, AL);
    }
}

__global__ void scan1(const int* __restrict__ counts, int* __restrict__ indptr,
                      int* __restrict__ bsums) {
    __shared__ int sd[256];
    int t = threadIdx.x;
    int i = blockIdx.x * 256 + t;
    int v = (i < N_NODES) ? counts[i] : 0;
    sd[t] = v;
    __syncthreads();
    for (int o = 1; o < 256; o <<= 1) {
        int x = (t >= o) ? sd[t - o] : 0;
        __syncthreads();
        sd[t] += x;
        __syncthreads();
    }
    int incl = sd[t];
    if (i < N_NODES) indptr[i] = incl - v;   // block-local exclusive
    if (t == 255) bsums[blockIdx.x] = incl;  // block total
}

// scan3 absorbs scan2: each block re-scans the 196 block sums.
__global__ void scan3(int* __restrict__ indptr, const int* __restrict__ bsums,
                      int* __restrict__ cursor) {
    __shared__ int sd[256];
    int t = threadIdx.x;
    int v = (t < NB_SCAN) ? bsums[t] : 0;
    sd[t] = v;
    __syncthreads();
    for (int o = 1; o < 256; o <<= 1) {
        int x = (t >= o) ? sd[t - o] : 0;
        __syncthreads();
        sd[t] += x;
        __syncthreads();
    }
    int off = (blockIdx.x == 0) ? 0 : sd[blockIdx.x - 1];  // exclusive prefix
    int i = blockIdx.x * 256 + t;
    if (i < N_NODES) {
        int val = indptr[i] + off;
        indptr[i] = val;
        cursor[i] = val;
    }
    if (i == 0) indptr[N_NODES] = E_TOT;
}

__global__ void fill_edges(const int* __restrict__ ei, int* __restrict__ cursor,
                           int* __restrict__ esrc, int* __restrict__ edst,
                           const int* __restrict__ flag) {
    int t = blockIdx.x * 256 + threadIdx.x;
    if (t >= E_TOT) return;
    int sh = flag[0] ? 0 : 1;
    int src, dst;
    if (t < E_RAW) { src = ei[t << sh]; dst = ei[(E_RAW + t) << sh]; }
    else           { src = t - E_RAW; dst = src; }
    int pos = atomicAdd(&cursor[dst], 1);
    esrc[pos] = src;
    edst[pos] = dst;
}

// ---------------- Merged compute launches ----------------
// gemm_h<128> (blocks 0..781) + edge_weights L0 (rest). Independent.
__global__ void __launch_bounds__(256) gemm128_ew(
    const __half* __restrict__ Xh, const __half* __restrict__ Wtf,
    __half* __restrict__ H, const float* __restrict__ AL,
    const int* __restrict__ esrc, const int* __restrict__ edst,
    float4* __restrict__ EW) {
    __shared__ _Float16 lds[4 * 16 * 264];   // 33 KB (gemm branch only)
    if (blockIdx.x < NB_GEMH) {
        gemm_h_body<128>(blockIdx.x, lds, Xh, Wtf, H);
    } else {
        int p = (blockIdx.x - NB_GEMH) * 256 + threadIdx.x;
        ew_body(p, AL, esrc, edst, EW);
    }
}

// al_gemm64 (blocks 0..NB_AL-1) + gemm_h<64> (rest). Independent: both
// depend only on the preceding aggregate.
__global__ void __launch_bounds__(256) al64_gemm64(
    const float* __restrict__ X, const float* __restrict__ Wa,
    float* __restrict__ ALout, const __half* __restrict__ Xh16,
    const __half* __restrict__ Wtf, __half* __restrict__ H) {
    __shared__ _Float16 lds[4 * 16 * 264];
    if (blockIdx.x < NB_AL) {
        int nbase = blockIdx.x * 32 + (threadIdx.x >> 6) * 8;
        al64_body(nbase, X, Wa, ALout);
    } else {
        gemm_h_body<64>(blockIdx.x - NB_AL, lds, Xh16, Wtf, H);
    }
}

// standalone edge_weights (layers 1,2 — depends on al64 output)
__global__ void __launch_bounds__(256) edge_weights(
    const float* __restrict__ AL, const int* __restrict__ esrc,
    const int* __restrict__ edst, float4* __restrict__ EW) {
    int p = blockIdx.x * 256 + threadIdx.x;
    ew_body(p, AL, esrc, edst, EW);
}

// ---------------- Per-destination aggregation ----------------
// r14's bare body (68.2-69.5 us across 6 sessions; perturbations regress).
__global__ void __launch_bounds__(256) aggregate(
    const __half* __restrict__ H, const float4* __restrict__ EW,
    const int* __restrict__ indptr, const int* __restrict__ esrc,
    const float* __restrict__ bias, float* __restrict__ XOUT,
    __half* __restrict__ XOUT16) {
    int wave = threadIdx.x >> 6, lane = threadIdx.x & 63;
    int n = blockIdx.x * 4 + wave;   // 12500 * 4 == 50000 exactly

    int start = indptr[n], end = indptr[n + 1];
    const float2* H2 = (const float2*)H;    // 64 float2 per node row

    float d0 = 0.f, d1 = 0.f, d2 = 0.f, d3 = 0.f;
    float a0 = 0.f, a1 = 0.f, a2 = 0.f, a3 = 0.f;

#define EDGE_BODY(E, Hv)                                            \
    {                                                               \
        d0 += E.x; d1 += E.y; d2 += E.z; d3 += E.w;                 \
        float2 c01 = __half22float2(((const __half2*)&Hv)[0]);      \
        float2 c23 = __half22float2(((const __half2*)&Hv)[1]);      \
        a0 += E.x * c01.x; a1 += E.y * c01.y;                       \
        a2 += E.z * c23.x; a3 += E.w * c23.y;                       \
    }

    for (int cb = start; cb < end; cb += 64) {
        int cnt = end - cb; if (cnt > 64) cnt = 64;
        int my_s = (lane < cnt) ? esrc[cb + lane] : 0;
        for (int base = 0; base < cnt; base += 4) {
            int m = cnt - base;   // wave-uniform
            int r1 = (1 < m ? 1 : 0), r2 = (2 < m ? 2 : 0), r3 = (3 < m ? 3 : 0);
            int s0 = __shfl(my_s, base, 64);
            int s1 = __shfl(my_s, base + r1, 64);
            int s2 = __shfl(my_s, base + r2, 64);
            int s3 = __shfl(my_s, base + r3, 64);
            float4 E0 = EW[cb + base];                       // uniform -> bcast
            float4 E1 = EW[cb + base + r1];
            float4 E2 = EW[cb + base + r2];
            float4 E3 = EW[cb + base + r3];
            float2 H0 = H2[(s0 << 6) + lane];
            float2 H1 = H2[(s1 << 6) + lane];
            float2 H2v = H2[(s2 << 6) + lane];
            float2 H3 = H2[(s3 << 6) + lane];
            EDGE_BODY(E0, H0);
            if (m > 1) EDGE_BODY(E1, H1);
            if (m > 2) EDGE_BODY(E2, H2v);
            if (m > 3) EDGE_BODY(E3, H3);
        }
    }
#undef EDGE_BODY

    float r = a0 / d0 + a1 / d1 + a2 / d2 + a3 / d3;
    r = 0.25f * r + bias[lane];
    r = r > 0.f ? r : (__expf(r) - 1.f);   // ELU
    XOUT[n * 64 + lane] = r;
    if (XOUT16) XOUT16[n * 64 + lane] = __float2half(r);
}

// ---------------- Final FC ----------------
__global__ void __launch_bounds__(256) fc_kernel(
    const float* __restrict__ X, const float* __restrict__ fcW,
    const float* __restrict__ fcb, float* __restrict__ OUT) {
    __shared__ float ws[64 * 10];
    __shared__ float bs[10];
    int t = threadIdx.x;
    for (int i = t; i < 640; i += 256) ws[i] = fcW[i];   // 640 > blockDim
    if (t < 10) bs[t] = fcb[t];
    __syncthreads();
    int n = blockIdx.x * 256 + t;
    if (n >= N_NODES) return;
    float acc[10];
#pragma unroll
    for (int c = 0; c < 10; c++) acc[c] = bs[c];
    for (int d = 0; d < 64; d++) {
        float x = X[n * 64 + d];
#pragma unroll
        for (int c = 0; c < 10; c++) acc[c] += x * ws[d * 10 + c];
    }
#pragma unroll
    for (int c = 0; c < 10; c++) OUT[n * 10 + c] = acc[c];
}

// ---------------- Launch ----------------
extern "C" void kernel_launch(void* const* d_in, const int* in_sizes, int n_in,
                              void* d_out, int out_size, void* d_ws, size_t ws_size,
                              hipStream_t stream) {
    const float* x     = (const float*)d_in[0];
    const int*   ei    = (const int*)d_in[1];
    const float* W[3]    = {(const float*)d_in[2], (const float*)d_in[6], (const float*)d_in[10]};
    const float* asrc[3] = {(const float*)d_in[3], (const float*)d_in[7], (const float*)d_in[11]};
    const float* adst[3] = {(const float*)d_in[4], (const float*)d_in[8], (const float*)d_in[12]};
    const float* bias[3] = {(const float*)d_in[5], (const float*)d_in[9], (const float*)d_in[13]};
    const float* fcW = (const float*)d_in[14];
    const float* fcb = (const float*)d_in[15];
    float* out = (float*)d_out;

    char* ws = (char*)d_ws;
    size_t off = 0;
    auto alloc = [&](size_t bytes) {
        void* p = ws + off;
        off = (off + bytes + 255) & ~(size_t)255;
        return p;
    };
    __half* H     = (__half*)alloc((size_t)N_NODES * 256 * 2);  // 25.6 MB fp16
    float*  AL    = (float*)alloc((size_t)N_NODES * 8 * 4);     // 1.6 MB
    float4* EW    = (float4*)alloc((size_t)E_TOT * 16);         // 13.6 MB
    float*  XA    = (float*)alloc((size_t)N_NODES * 64 * 4);    // 12.8 MB
    float*  XB    = (float*)alloc((size_t)N_NODES * 64 * 4);    // 12.8 MB
    __half* Xh0   = (__half*)alloc((size_t)N_NODES * 128 * 2);  // 12.8 MB
    __half* XA16  = (__half*)alloc((size_t)N_NODES * 64 * 2);   // 6.4 MB
    __half* XB16  = (__half*)alloc((size_t)N_NODES * 64 * 2);   // 6.4 MB
    __half* Wtf0  = (__half*)alloc(4096 * 8 * 2);
    __half* Wtf1  = (__half*)alloc(2048 * 8 * 2);
    __half* Wtf2  = (__half*)alloc(2048 * 8 * 2);
    float*  Wa0   = (float*)alloc(128 * 8 * 4);
    float*  Wa1   = (float*)alloc(64 * 8 * 4);
    float*  Wa2   = (float*)alloc(64 * 8 * 4);
    int* counts = (int*)alloc((size_t)N_NODES * 4);
    int* indptr = (int*)alloc((size_t)(N_NODES + 1) * 4);
    int* cursor = (int*)alloc((size_t)N_NODES * 4);
    int* esrc   = (int*)alloc((size_t)E_TOT * 4);
    int* edst   = (int*)alloc((size_t)E_TOT * 4);
    int* bsums  = (int*)alloc(256 * 4);
    int* flag   = (int*)alloc(256 * 4);

    // Prep + CSR build (count_edges merged with cast_al — independent)
    prep_kernel<<<485, 256, 0, stream>>>(ei, counts, flag, W[0], W[1], W[2],
                                         Wtf0, Wtf1, Wtf2,
                                         asrc[0], adst[0], asrc[1], adst[1],
                                         asrc[2], adst[2], Wa0, Wa1, Wa2);
    count_cast<<<NB_EDGE + NB_AL, 256, 0, stream>>>(ei, counts, flag,
                                                    x, Wa0, Xh0, AL);
    scan1<<<NB_SCAN, 256, 0, stream>>>(counts, indptr, bsums);
    scan3<<<NB_SCAN, 256, 0, stream>>>(indptr, bsums, cursor);
    fill_edges<<<NB_EDGE, 256, 0, stream>>>(ei, cursor, esrc, edst, flag);

    // Layer 0 (gemm_h<128> merged with EW — independent)
    gemm128_ew<<<NB_GEMH + NB_EDGE, 256, 0, stream>>>(Xh0, Wtf0, H,
                                                      AL, esrc, edst, EW);
    aggregate<<<NB_NODE, 256, 0, stream>>>(H, EW, indptr, esrc, bias[0], XA, XA16);
    // Layer 1 (al_gemm64 merged with gemm_h<64>)
    al64_gemm64<<<NB_AL + NB_GEMH, 256, 0, stream>>>(XA, Wa1, AL,
                                                     XA16, Wtf1, H);
    edge_weights<<<NB_EDGE, 256, 0, stream>>>(AL, esrc, edst, EW);
    aggregate<<<NB_NODE, 256, 0, stream>>>(H, EW, indptr, esrc, bias[1], XB, XB16);
    // Layer 2
    al64_gemm64<<<NB_AL + NB_GEMH, 256, 0, stream>>>(XB, Wa2, AL,
                                                     XB16, Wtf2, H);
    edge_weights<<<NB_EDGE, 256, 0, stream>>>(AL, esrc, edst, EW);
    aggregate<<<NB_NODE, 256, 0, stream>>>(H, EW, indptr, esrc, bias[2], XA, nullptr);

    // Final FC
    fc_kernel<<<NB_SCAN, 256, 0, stream>>>(XA, fcW, fcb, out);
}

// Round 23
// 486.417 us; speedup vs baseline: 1.0017x; 1.0017x over previous
//
#include <hip/hip_runtime.h>
#include <hip/hip_fp16.h>
#include <math.h>

// Problem constants (from reference)
#define N_NODES 50000
#define IN_DIM  128
#define HIDDEN  64
#define OUT_DIM 10
#define HEADS   4
#define E_RAW   800000
#define E_TOT   (E_RAW + N_NODES)   // with self-loops: 850000
#define NEG_SLOPE 0.2f

#define NB_SCAN 196    // ceil(50000/256)
#define NB_EDGE 3321   // ceil(850000/256)
#define NB_ERAW 3125   // 800000/256 (real edges only; self-loops pre-counted)
#define NB_GEMH 782    // ceil(50000/64)
#define NB_NODE 12500  // 50000/4 (one wave per node)
#define NB_AL   1563   // ceil(50000/32) -- 32 nodes/block (8 lanes/node)

typedef _Float16 half8 __attribute__((ext_vector_type(8)));
typedef float floatx4 __attribute__((ext_vector_type(4)));

// ---------------- Fused prep: init counts | detect dtype | Wtf | Wa --------
__global__ void prep_kernel(const int* __restrict__ ei, int* __restrict__ counts,
                            int* __restrict__ flag,
                            const float* __restrict__ W0, const float* __restrict__ W1,
                            const float* __restrict__ W2,
                            __half* __restrict__ Wtf0, __half* __restrict__ Wtf1,
                            __half* __restrict__ Wtf2,
                            const float* __restrict__ as0, const float* __restrict__ ad0,
                            const float* __restrict__ as1, const float* __restrict__ ad1,
                            const float* __restrict__ as2, const float* __restrict__ ad2,
                            float* __restrict__ Wa0, float* __restrict__ Wa1,
                            float* __restrict__ Wa2) {
    int bid = blockIdx.x, t = threadIdx.x;
    if (bid < 196) {                       // counts = 1 (self-loop pre-counted)
        int i = bid * 256 + t;
        if (i < N_NODES) counts[i] = 1;
    } else if (bid == 196) {               // dtype detect: flag=1 -> int32
        __shared__ int anyv;
        if (t == 0) anyv = 0;
        __syncthreads();
        int idx = 2 * (t * 3100 + 17) + 1; // odd word, < 1.6M
        if (ei[idx] != 0) atomicOr(&anyv, 1);
        __syncthreads();
        if (t == 0) flag[0] = anyv;        // plain store: no pre-zero needed
    } else if (bid < 229) {                // Wtf fragments (MFMA B order)
        int i = (bid - 197) * 256 + t;
        int K, f;
        const float* W; __half* Wtf;
        if (i < 4096)      { f = i;        K = 128; W = W0; Wtf = Wtf0; }
        else if (i < 6144) { f = i - 4096; K = 64;  W = W1; Wtf = Wtf1; }
        else if (i < 8192) { f = i - 6144; K = 64;  W = W2; Wtf = Wtf2; }
        else return;
        int KC = K / 32;
        int lane = f & 63, kc = (f >> 6) % KC, ct = f / (64 * KC);
        int m = lane & 15, quad = lane >> 4;
        int col = ct * 16 + m;
        __half tmp[8];
#pragma unroll
        for (int j = 0; j < 8; j++)
            tmp[j] = __float2half(W[(kc * 32 + quad * 8 + j) * 256 + col]);
        *(uint4*)(Wtf + (size_t)f * 8) = *(uint4*)tmp;
    } else {                               // Wa: one block per (layer,k)
        int b = bid - 229;                 // 0..255
        int l, k;
        if (b < 128)      { l = 0; k = b; }
        else if (b < 192) { l = 1; k = b - 128; }
        else              { l = 2; k = b - 192; }
        const float* W  = (l == 0) ? W0 : (l == 1) ? W1 : W2;
        const float* as = (l == 0) ? as0 : (l == 1) ? as1 : as2;
        const float* ad = (l == 0) ? ad0 : (l == 1) ? ad1 : ad2;
        float* Wa       = (l == 0) ? Wa0 : (l == 1) ? Wa1 : Wa2;
        int h = t >> 6, d = t & 63;
        float wv = W[k * 256 + h * 64 + d];
        float ss = wv * as[h * 64 + d];
        float dd = wv * ad[h * 64 + d];
#pragma unroll
        for (int o = 1; o < 64; o <<= 1) {
            ss += __shfl_xor(ss, o, 64);
            dd += __shfl_xor(dd, o, 64);
        }
        if (d == 0) {
            Wa[k * 8 + h]     = ss;
            Wa[k * 8 + 4 + h] = dd;
        }
    }
}

// ---------------- Device bodies (shared by merged kernels) ----------------

// cast_al body, 8-lanes-per-node (coalesced; r22)
__device__ __forceinline__ void cast_al_body(
    int nbase, const float* __restrict__ X, const float* __restrict__ Wa,
    __half* __restrict__ Xh, float* __restrict__ AL) {
    int lane = threadIdx.x & 63;
    int ns = lane >> 3, j = lane & 7;     // node-sub, owned column
    int n = nbase + ns;
    if (n >= N_NODES) return;
    const float4* X4 = (const float4*)(X + (size_t)n * 128);
    float s = 0.f;
#pragma unroll 8
    for (int k4 = 0; k4 < 32; k4++) {
        float4 v = X4[k4];
        s += v.x * Wa[(k4 * 4 + 0) * 8 + j] + v.y * Wa[(k4 * 4 + 1) * 8 + j]
           + v.z * Wa[(k4 * 4 + 2) * 8 + j] + v.w * Wa[(k4 * 4 + 3) * 8 + j];
    }
    AL[n * 8 + j] = s;
#pragma unroll
    for (int c = 0; c < 2; c++) {
        float4 va = X4[j * 4 + c * 2], vb = X4[j * 4 + c * 2 + 1];
        __half2 hh[4] = {__float22half2_rn(make_float2(va.x, va.y)),
                         __float22half2_rn(make_float2(va.z, va.w)),
                         __float22half2_rn(make_float2(vb.x, vb.y)),
                         __float22half2_rn(make_float2(vb.z, vb.w))};
        *(uint4*)(Xh + (size_t)n * 128 + j * 16 + c * 8) = *(uint4*)hh;
    }
}

// al_gemm64 body, 8-lanes-per-node (K=64)
__device__ __forceinline__ void al64_body(
    int nbase, const float* __restrict__ X, const float* __restrict__ Wa,
    float* __restrict__ AL) {
    int lane = threadIdx.x & 63;
    int ns = lane >> 3, j = lane & 7;
    int n = nbase + ns;
    if (n >= N_NODES) return;
    const float4* X4 = (const float4*)(X + (size_t)n * 64);
    float s = 0.f;
#pragma unroll 8
    for (int k4 = 0; k4 < 16; k4++) {
        float4 v = X4[k4];
        s += v.x * Wa[(k4 * 4 + 0) * 8 + j] + v.y * Wa[(k4 * 4 + 1) * 8 + j]
           + v.z * Wa[(k4 * 4 + 2) * 8 + j] + v.w * Wa[(k4 * 4 + 3) * 8 + j];
    }
    AL[n * 8 + j] = s;
}

// edge_weights body: EW[p] = exp(leaky(AL_src + AL_dst)) — no max shift
// (logits analytically bounded, validated rounds 4-22; exact-f32 logit path)
__device__ __forceinline__ void ew_body(
    int p, const float* __restrict__ AL, const int* __restrict__ esrc,
    const int* __restrict__ edst, float4* __restrict__ EW) {
    if (p >= E_TOT) return;
    int s = esrc[p], d = edst[p];
    const float4* AL4 = (const float4*)AL;
    float4 as = AL4[s * 2];
    float4 ad = AL4[d * 2 + 1];
    float v0 = as.x + ad.x; v0 = fmaxf(v0, NEG_SLOPE * v0);
    float v1 = as.y + ad.y; v1 = fmaxf(v1, NEG_SLOPE * v1);
    float v2 = as.z + ad.z; v2 = fmaxf(v2, NEG_SLOPE * v2);
    float v3 = as.w + ad.w; v3 = fmaxf(v3, NEG_SLOPE * v3);
    EW[p] = make_float4(__expf(v0), __expf(v1), __expf(v2), __expf(v3));
}

// fill_edges body
__device__ __forceinline__ void fill_body(
    int t, const int* __restrict__ ei, int* __restrict__ cursor,
    int* __restrict__ esrc, int* __restrict__ edst,
    const int* __restrict__ flag) {
    if (t >= E_TOT) return;
    int sh = flag[0] ? 0 : 1;
    int src, dst;
    if (t < E_RAW) { src = ei[t << sh]; dst = ei[(E_RAW + t) << sh]; }
    else           { src = t - E_RAW; dst = src; }
    int pos = atomicAdd(&cursor[dst], 1);
    esrc[pos] = src;
    edst[pos] = dst;
}

// gemm_h body (r18/r20 version — MFMA math verified, bank-padded epilogue)
template <int K>
__device__ __forceinline__ void gemm_h_body(
    int bid, _Float16* lds, const __half* __restrict__ Xh,
    const __half* __restrict__ Wtf, __half* __restrict__ H) {
    const int KC = K / 32;
    const int CTC = (K == 128) ? 8 : 16;
    const int NCHUNK = 16 / CTC;
    int t = threadIdx.x;
    int w = t >> 6, lane = t & 63;
    int m = lane & 15, quad = lane >> 4;
    int n0 = bid * 64;
    int nr = n0 + w * 16 + m;
    int nc = (nr < N_NODES) ? nr : (N_NODES - 1);

    half8 afrag[KC];
#pragma unroll
    for (int kc = 0; kc < KC; kc++)
        afrag[kc] = *(const half8*)(Xh + (size_t)nc * K + kc * 32 + quad * 8);

    floatx4 accs[16];
    const uint4* Wg = (const uint4*)Wtf;
#pragma unroll
    for (int c = 0; c < NCHUNK; c++) {
        __syncthreads();
        uint4* dstl = (uint4*)lds;
        const uint4* srcg = Wg + (size_t)c * 2048;
#pragma unroll
        for (int q = 0; q < 8; q++) dstl[t + 256 * q] = srcg[t + 256 * q];
        __syncthreads();
#pragma unroll
        for (int ctl = 0; ctl < CTC; ctl++) {
            floatx4 acc = {0.f, 0.f, 0.f, 0.f};
#pragma unroll
            for (int kc = 0; kc < KC; kc++) {
                half8 b = *(const half8*)&lds[((ctl * KC + kc) * 64 + lane) * 8];
                acc = __builtin_amdgcn_mfma_f32_16x16x32_f16(afrag[kc], b, acc, 0, 0, 0);
            }
            accs[c * CTC + ctl] = acc;
        }
    }
    __syncthreads();
    _Float16* myl = lds + w * (16 * 264);
#pragma unroll
    for (int ct = 0; ct < 16; ct++) {
        int cc = ct * 16 + m;            // GEMM col = h*64 + d
        int h = cc >> 6, d = cc & 63;
        int pos = d * 4 + h;             // H dim-major position
        int q = pos >> 6, o = pos & 63;  // padded quarter q at q*66
#pragma unroll
        for (int i = 0; i < 4; i++)
            myl[(quad * 4 + i) * 264 + q * 66 + o] = (_Float16)accs[ct][i];
    }
    __syncthreads();
    int r = t >> 2, p = t & 3;
    int n2 = n0 + r;
    if (n2 < N_NODES) {
        const _Float16* src = lds + (r >> 4) * (16 * 264) + (r & 15) * 264 + p * 66;
        uint4* dst = (uint4*)(H + (size_t)n2 * 256 + p * 64);
#pragma unroll
        for (int j = 0; j < 8; j++) dst[j] = ((const uint4*)src)[j];
    }
}

// ---------------- CSR build ----------------

// Merged: count_edges (real edges only; blocks 0..NB_ERAW-1) + cast_al.
__global__ void __launch_bounds__(256) count_cast(
    const int* __restrict__ ei, int* __restrict__ counts,
    const int* __restrict__ flag, const float* __restrict__ X,
    const float* __restrict__ Wa0, __half* __restrict__ Xh,
    float* __restrict__ AL) {
    if (blockIdx.x < NB_ERAW) {
        int t = blockIdx.x * 256 + threadIdx.x;   // t < 800000 exactly
        int sh = flag[0] ? 0 : 1;             // int32 -> 0, int64 -> 1
        int dst = ei[(E_RAW + t) << sh];
        atomicAdd(&counts[dst], 1);
    } else {
        int nbase = (blockIdx.x - NB_ERAW) * 32 + (threadIdx.x >> 6) * 8;
        cast_al_body(nbase, X, Wa0, Xh, AL);
    }
}

__global__ void scan1(const int* __restrict__ counts, int* __restrict__ indptr,
                      int* __restrict__ bsums) {
    __shared__ int sd[256];
    int t = threadIdx.x;
    int i = blockIdx.x * 256 + t;
    int v = (i < N_NODES) ? counts[i] : 0;
    sd[t] = v;
    __syncthreads();
    for (int o = 1; o < 256; o <<= 1) {
        int x = (t >= o) ? sd[t - o] : 0;
        __syncthreads();
        sd[t] += x;
        __syncthreads();
    }
    int incl = sd[t];
    if (i < N_NODES) indptr[i] = incl - v;   // block-local exclusive
    if (t == 255) bsums[blockIdx.x] = incl;  // block total
}

// scan3 absorbs scan2: each block re-scans the 196 block sums.
__global__ void scan3(int* __restrict__ indptr, const int* __restrict__ bsums,
                      int* __restrict__ cursor) {
    __shared__ int sd[256];
    int t = threadIdx.x;
    int v = (t < NB_SCAN) ? bsums[t] : 0;
    sd[t] = v;
    __syncthreads();
    for (int o = 1; o < 256; o <<= 1) {
        int x = (t >= o) ? sd[t - o] : 0;
        __syncthreads();
        sd[t] += x;
        __syncthreads();
    }
    int off = (blockIdx.x == 0) ? 0 : sd[blockIdx.x - 1];  // exclusive prefix
    int i = blockIdx.x * 256 + t;
    if (i < N_NODES) {
        int val = indptr[i] + off;
        indptr[i] = val;
        cursor[i] = val;
    }
    if (i == 0) indptr[N_NODES] = E_TOT;
}

// Merged: fill_edges (blocks 0..NB_EDGE-1) + gemm_h<128> (rest).
// Independent: fill needs cursor (scan3) + ei; gemm needs Xh0 (count_cast)
// + Wtf0 (prep). fill's latency-bound scattered atomics/writes hide under
// gemm's MFMA work instead of running alone (r22: fill serialized ~35 us).
__global__ void __launch_bounds__(256) fill_gemm128(
    const int* __restrict__ ei, int* __restrict__ cursor,
    int* __restrict__ esrc, int* __restrict__ edst,
    const int* __restrict__ flag, const __half* __restrict__ Xh,
    const __half* __restrict__ Wtf, __half* __restrict__ H) {
    __shared__ _Float16 lds[4 * 16 * 264];   // gemm branch only
    if (blockIdx.x < NB_EDGE) {
        int t = blockIdx.x * 256 + threadIdx.x;
        fill_body(t, ei, cursor, esrc, edst, flag);
    } else {
        gemm_h_body<128>(blockIdx.x - NB_EDGE, lds, Xh, Wtf, H);
    }
}

// al_gemm64 (blocks 0..NB_AL-1) + gemm_h<64> (rest). Independent.
__global__ void __launch_bounds__(256) al64_gemm64(
    const float* __restrict__ X, const float* __restrict__ Wa,
    float* __restrict__ ALout, const __half* __restrict__ Xh16,
    const __half* __restrict__ Wtf, __half* __restrict__ H) {
    __shared__ _Float16 lds[4 * 16 * 264];
    if (blockIdx.x < NB_AL) {
        int nbase = blockIdx.x * 32 + (threadIdx.x >> 6) * 8;
        al64_body(nbase, X, Wa, ALout);
    } else {
        gemm_h_body<64>(blockIdx.x - NB_AL, lds, Xh16, Wtf, H);
    }
}

// standalone edge_weights
__global__ void __launch_bounds__(256) edge_weights(
    const float* __restrict__ AL, const int* __restrict__ esrc,
    const int* __restrict__ edst, float4* __restrict__ EW) {
    int p = blockIdx.x * 256 + threadIdx.x;
    ew_body(p, AL, esrc, edst, EW);
}

// ---------------- Per-destination aggregation ----------------
// r14's bare body (68.2-70.0 us across 7 sessions; perturbations regress).
__global__ void __launch_bounds__(256) aggregate(
    const __half* __restrict__ H, const float4* __restrict__ EW,
    const int* __restrict__ indptr, const int* __restrict__ esrc,
    const float* __restrict__ bias, float* __restrict__ XOUT,
    __half* __restrict__ XOUT16) {
    int wave = threadIdx.x >> 6, lane = threadIdx.x & 63;
    int n = blockIdx.x * 4 + wave;   // 12500 * 4 == 50000 exactly

    int start = indptr[n], end = indptr[n + 1];
    const float2* H2 = (const float2*)H;    // 64 float2 per node row

    float d0 = 0.f, d1 = 0.f, d2 = 0.f, d3 = 0.f;
    float a0 = 0.f, a1 = 0.f, a2 = 0.f, a3 = 0.f;

#define EDGE_BODY(E, Hv)                                            \
    {                                                               \
        d0 += E.x; d1 += E.y; d2 += E.z; d3 += E.w;                 \
        float2 c01 = __half22float2(((const __half2*)&Hv)[0]);      \
        float2 c23 = __half22float2(((const __half2*)&Hv)[1]);      \
        a0 += E.x * c01.x; a1 += E.y * c01.y;                       \
        a2 += E.z * c23.x; a3 += E.w * c23.y;                       \
    }

    for (int cb = start; cb < end; cb += 64) {
        int cnt = end - cb; if (cnt > 64) cnt = 64;
        int my_s = (lane < cnt) ? esrc[cb + lane] : 0;
        for (int base = 0; base < cnt; base += 4) {
            int m = cnt - base;   // wave-uniform
            int r1 = (1 < m ? 1 : 0), r2 = (2 < m ? 2 : 0), r3 = (3 < m ? 3 : 0);
            int s0 = __shfl(my_s, base, 64);
            int s1 = __shfl(my_s, base + r1, 64);
            int s2 = __shfl(my_s, base + r2, 64);
            int s3 = __shfl(my_s, base + r3, 64);
            float4 E0 = EW[cb + base];                       // uniform -> bcast
            float4 E1 = EW[cb + base + r1];
            float4 E2 = EW[cb + base + r2];
            float4 E3 = EW[cb + base + r3];
            float2 H0 = H2[(s0 << 6) + lane];
            float2 H1 = H2[(s1 << 6) + lane];
            float2 H2v = H2[(s2 << 6) + lane];
            float2 H3 = H2[(s3 << 6) + lane];
            EDGE_BODY(E0, H0);
            if (m > 1) EDGE_BODY(E1, H1);
            if (m > 2) EDGE_BODY(E2, H2v);
            if (m > 3) EDGE_BODY(E3, H3);
        }
    }
#undef EDGE_BODY

    float r = a0 / d0 + a1 / d1 + a2 / d2 + a3 / d3;
    r = 0.25f * r + bias[lane];
    r = r > 0.f ? r : (__expf(r) - 1.f);   // ELU
    XOUT[n * 64 + lane] = r;
    if (XOUT16) XOUT16[n * 64 + lane] = __float2half(r);
}

// ---------------- Final FC ----------------
__global__ void __launch_bounds__(256) fc_kernel(
    const float* __restrict__ X, const float* __restrict__ fcW,
    const float* __restrict__ fcb, float* __restrict__ OUT) {
    __shared__ float ws[64 * 10];
    __shared__ float bs[10];
    int t = threadIdx.x;
    for (int i = t; i < 640; i += 256) ws[i] = fcW[i];   // 640 > blockDim
    if (t < 10) bs[t] = fcb[t];
    __syncthreads();
    int n = blockIdx.x * 256 + t;
    if (n >= N_NODES) return;
    float acc[10];
#pragma unroll
    for (int c = 0; c < 10; c++) acc[c] = bs[c];
    for (int d = 0; d < 64; d++) {
        float x = X[n * 64 + d];
#pragma unroll
        for (int c = 0; c < 10; c++) acc[c] += x * ws[d * 10 + c];
    }
#pragma unroll
    for (int c = 0; c < 10; c++) OUT[n * 10 + c] = acc[c];
}

// ---------------- Launch ----------------
extern "C" void kernel_launch(void* const* d_in, const int* in_sizes, int n_in,
                              void* d_out, int out_size, void* d_ws, size_t ws_size,
                              hipStream_t stream) {
    const float* x     = (const float*)d_in[0];
    const int*   ei    = (const int*)d_in[1];
    const float* W[3]    = {(const float*)d_in[2], (const float*)d_in[6], (const float*)d_in[10]};
    const float* asrc[3] = {(const float*)d_in[3], (const float*)d_in[7], (const float*)d_in[11]};
    const float* adst[3] = {(const float*)d_in[4], (const float*)d_in[8], (const float*)d_in[12]};
    const float* bias[3] = {(const float*)d_in[5], (const float*)d_in[9], (const float*)d_in[13]};
    const float* fcW = (const float*)d_in[14];
    const float* fcb = (const float*)d_in[15];
    float* out = (float*)d_out;

    char* ws = (char*)d_ws;
    size_t off = 0;
    auto alloc = [&](size_t bytes) {
        void* p = ws + off;
        off = (off + bytes + 255) & ~(size_t)255;
        return p;
    };
    __half* H     = (__half*)alloc((size_t)N_NODES * 256 * 2);  // 25.6 MB fp16
    float*  AL    = (float*)alloc((size_t)N_NODES * 8 * 4);     // 1.6 MB
    float4* EW    = (float4*)alloc((size_t)E_TOT * 16);         // 13.6 MB
    float*  XA    = (float*)alloc((size_t)N_NODES * 64 * 4);    // 12.8 MB
    float*  XB    = (float*)alloc((size_t)N_NODES * 64 * 4);    // 12.8 MB
    __half* Xh0   = (__half*)alloc((size_t)N_NODES * 128 * 2);  // 12.8 MB
    __half* XA16  = (__half*)alloc((size_t)N_NODES * 64 * 2);   // 6.4 MB
    __half* XB16  = (__half*)alloc((size_t)N_NODES * 64 * 2);   // 6.4 MB
    __half* Wtf0  = (__half*)alloc(4096 * 8 * 2);
    __half* Wtf1  = (__half*)alloc(2048 * 8 * 2);
    __half* Wtf2  = (__half*)alloc(2048 * 8 * 2);
    float*  Wa0   = (float*)alloc(128 * 8 * 4);
    float*  Wa1   = (float*)alloc(64 * 8 * 4);
    float*  Wa2   = (float*)alloc(64 * 8 * 4);
    int* counts = (int*)alloc((size_t)N_NODES * 4);
    int* indptr = (int*)alloc((size_t)(N_NODES + 1) * 4);
    int* cursor = (int*)alloc((size_t)N_NODES * 4);
    int* esrc   = (int*)alloc((size_t)E_TOT * 4);
    int* edst   = (int*)alloc((size_t)E_TOT * 4);
    int* bsums  = (int*)alloc(256 * 4);
    int* flag   = (int*)alloc(256 * 4);

    // Prep + CSR build
    prep_kernel<<<485, 256, 0, stream>>>(ei, counts, flag, W[0], W[1], W[2],
                                         Wtf0, Wtf1, Wtf2,
                                         asrc[0], adst[0], asrc[1], adst[1],
                                         asrc[2], adst[2], Wa0, Wa1, Wa2);
    count_cast<<<NB_ERAW + NB_AL, 256, 0, stream>>>(ei, counts, flag,
                                                    x, Wa0, Xh0, AL);
    scan1<<<NB_SCAN, 256, 0, stream>>>(counts, indptr, bsums);
    scan3<<<NB_SCAN, 256, 0, stream>>>(indptr, bsums, cursor);

    // Layer 0 (fill_edges merged with gemm_h<128> — independent)
    fill_gemm128<<<NB_EDGE + NB_GEMH, 256, 0, stream>>>(ei, cursor, esrc, edst,
                                                        flag, Xh0, Wtf0, H);
    edge_weights<<<NB_EDGE, 256, 0, stream>>>(AL, esrc, edst, EW);
    aggregate<<<NB_NODE, 256, 0, stream>>>(H, EW, indptr, esrc, bias[0], XA, XA16);
    // Layer 1 (al_gemm64 merged with gemm_h<64>)
    al64_gemm64<<<NB_AL + NB_GEMH, 256, 0, stream>>>(XA, Wa1, AL,
                                                     XA16, Wtf1, H);
    edge_weights<<<NB_EDGE, 256, 0, stream>>>(AL, esrc, edst, EW);
    aggregate<<<NB_NODE, 256, 0, stream>>>(H, EW, indptr, esrc, bias[1], XB, XB16);
    // Layer 2
    al64_gemm64<<<NB_AL + NB_GEMH, 256, 0, stream>>>(XB, Wa2, AL,
                                                     XB16, Wtf2, H);
    edge_weights<<<NB_EDGE, 256, 0, stream>>>(AL, esrc, edst, EW);
    aggregate<<<NB_NODE, 256, 0, stream>>>(H, EW, indptr, esrc, bias[2], XA, nullptr);

    // Final FC
    fc_kernel<<<NB_SCAN, 256, 0, stream>>>(XA, fcW, fcb, out);
}

// Round 24
// 476.884 us; speedup vs baseline: 1.0217x; 1.0200x over previous
//
#include <hip/hip_runtime.h>
#include <hip/hip_fp16.h>
#include <math.h>

// Problem constants (from reference)
#define N_NODES 50000
#define IN_DIM  128
#define HIDDEN  64
#define OUT_DIM 10
#define HEADS   4
#define E_RAW   800000
#define E_TOT   (E_RAW + N_NODES)   // with self-loops: 850000
#define NEG_SLOPE 0.2f

#define NB_SCAN 196    // ceil(50000/256)
#define NB_EDGE 3321   // ceil(850000/256)
#define NB_GEMH 782    // ceil(50000/64)
#define NB_NODE 12500  // 50000/4 (one wave per node)

typedef _Float16 half8 __attribute__((ext_vector_type(8)));
typedef float floatx4 __attribute__((ext_vector_type(4)));

// ---------------- Fused prep: zero counts | detect dtype | Wtf | Wa --------
__global__ void prep_kernel(const int* __restrict__ ei, int* __restrict__ counts,
                            int* __restrict__ flag,
                            const float* __restrict__ W0, const float* __restrict__ W1,
                            const float* __restrict__ W2,
                            __half* __restrict__ Wtf0, __half* __restrict__ Wtf1,
                            __half* __restrict__ Wtf2,
                            const float* __restrict__ as0, const float* __restrict__ ad0,
                            const float* __restrict__ as1, const float* __restrict__ ad1,
                            const float* __restrict__ as2, const float* __restrict__ ad2,
                            float* __restrict__ Wa0, float* __restrict__ Wa1,
                            float* __restrict__ Wa2) {
    int bid = blockIdx.x, t = threadIdx.x;
    if (bid < 196) {                       // zero counts
        int i = bid * 256 + t;
        if (i < N_NODES) counts[i] = 0;
    } else if (bid == 196) {               // dtype detect: flag=1 -> int32
        __shared__ int anyv;
        if (t == 0) anyv = 0;
        __syncthreads();
        int idx = 2 * (t * 3100 + 17) + 1; // odd word, < 1.6M
        if (ei[idx] != 0) atomicOr(&anyv, 1);
        __syncthreads();
        if (t == 0) flag[0] = anyv;        // plain store: no pre-zero needed
    } else if (bid < 229) {                // Wtf fragments (MFMA B order)
        int i = (bid - 197) * 256 + t;
        int K, f;
        const float* W; __half* Wtf;
        if (i < 4096)      { f = i;        K = 128; W = W0; Wtf = Wtf0; }
        else if (i < 6144) { f = i - 4096; K = 64;  W = W1; Wtf = Wtf1; }
        else if (i < 8192) { f = i - 6144; K = 64;  W = W2; Wtf = Wtf2; }
        else return;
        int KC = K / 32;
        int lane = f & 63, kc = (f >> 6) % KC, ct = f / (64 * KC);
        int m = lane & 15, quad = lane >> 4;
        int col = ct * 16 + m;
        __half tmp[8];
#pragma unroll
        for (int j = 0; j < 8; j++)
            tmp[j] = __float2half(W[(kc * 32 + quad * 8 + j) * 256 + col]);
        *(uint4*)(Wtf + (size_t)f * 8) = *(uint4*)tmp;
    } else {                               // Wa: one block per (layer,k)
        int b = bid - 229;                 // 0..255
        int l, k;
        if (b < 128)      { l = 0; k = b; }
        else if (b < 192) { l = 1; k = b - 128; }
        else              { l = 2; k = b - 192; }
        const float* W  = (l == 0) ? W0 : (l == 1) ? W1 : W2;
        const float* as = (l == 0) ? as0 : (l == 1) ? as1 : as2;
        const float* ad = (l == 0) ? ad0 : (l == 1) ? ad1 : ad2;
        float* Wa       = (l == 0) ? Wa0 : (l == 1) ? Wa1 : Wa2;
        int h = t >> 6, d = t & 63;
        float wv = W[k * 256 + h * 64 + d];
        float ss = wv * as[h * 64 + d];
        float dd = wv * ad[h * 64 + d];
#pragma unroll
        for (int o = 1; o < 64; o <<= 1) {
            ss += __shfl_xor(ss, o, 64);
            dd += __shfl_xor(dd, o, 64);
        }
        if (d == 0) {
            Wa[k * 8 + h]     = ss;
            Wa[k * 8 + 4 + h] = dd;
        }
    }
}

// ---------------- Device bodies (shared by merged kernels) ----------------

// cast_al body: thread-per-node (r20's butterfly-free form)
__device__ __forceinline__ void cast_al_body(
    int n, const float* __restrict__ X, const float* __restrict__ Wa,
    __half* __restrict__ Xh, float* __restrict__ AL) {
    if (n >= N_NODES) return;
    const float4* X4 = (const float4*)(X + (size_t)n * 128);
    __half2* xh2 = (__half2*)(Xh + (size_t)n * 128);
    float s[8];
#pragma unroll
    for (int j = 0; j < 8; j++) s[j] = 0.f;
#pragma unroll 4
    for (int k4 = 0; k4 < 32; k4++) {
        float4 v = X4[k4];
        xh2[k4 * 2]     = __float22half2_rn(make_float2(v.x, v.y));
        xh2[k4 * 2 + 1] = __float22half2_rn(make_float2(v.z, v.w));
#pragma unroll
        for (int j = 0; j < 8; j++)
            s[j] += v.x * Wa[(k4 * 4 + 0) * 8 + j] + v.y * Wa[(k4 * 4 + 1) * 8 + j]
                  + v.z * Wa[(k4 * 4 + 2) * 8 + j] + v.w * Wa[(k4 * 4 + 3) * 8 + j];
    }
    *(float4*)(AL + n * 8)     = make_float4(s[0], s[1], s[2], s[3]);
    *(float4*)(AL + n * 8 + 4) = make_float4(s[4], s[5], s[6], s[7]);
}

// al_gemm64 body: thread-per-node, K=64
__device__ __forceinline__ void al64_body(
    int n, const float* __restrict__ X, const float* __restrict__ Wa,
    float* __restrict__ AL) {
    if (n >= N_NODES) return;
    const float4* X4 = (const float4*)(X + (size_t)n * 64);
    float s[8];
#pragma unroll
    for (int j = 0; j < 8; j++) s[j] = 0.f;
#pragma unroll 4
    for (int k4 = 0; k4 < 16; k4++) {
        float4 v = X4[k4];
#pragma unroll
        for (int j = 0; j < 8; j++)
            s[j] += v.x * Wa[(k4 * 4 + 0) * 8 + j] + v.y * Wa[(k4 * 4 + 1) * 8 + j]
                  + v.z * Wa[(k4 * 4 + 2) * 8 + j] + v.w * Wa[(k4 * 4 + 3) * 8 + j];
    }
    *(float4*)(AL + n * 8)     = make_float4(s[0], s[1], s[2], s[3]);
    *(float4*)(AL + n * 8 + 4) = make_float4(s[4], s[5], s[6], s[7]);
}

// edge_weights body: EW[p] = exp(leaky(AL_src + AL_dst)) — no max shift
// (logits analytically bounded, validated rounds 4-23; exact-f32 logit path)
__device__ __forceinline__ void ew_body(
    int p, const float* __restrict__ AL, const int* __restrict__ esrc,
    const int* __restrict__ edst, float4* __restrict__ EW) {
    if (p >= E_TOT) return;
    int s = esrc[p], d = edst[p];
    const float4* AL4 = (const float4*)AL;
    float4 as = AL4[s * 2];
    float4 ad = AL4[d * 2 + 1];
    float v0 = as.x + ad.x; v0 = fmaxf(v0, NEG_SLOPE * v0);
    float v1 = as.y + ad.y; v1 = fmaxf(v1, NEG_SLOPE * v1);
    float v2 = as.z + ad.z; v2 = fmaxf(v2, NEG_SLOPE * v2);
    float v3 = as.w + ad.w; v3 = fmaxf(v3, NEG_SLOPE * v3);
    EW[p] = make_float4(__expf(v0), __expf(v1), __expf(v2), __expf(v3));
}

// gemm_h body (r18/r20 version — MFMA math verified, bank-padded epilogue)
template <int K>
__device__ __forceinline__ void gemm_h_body(
    int bid, _Float16* lds, const __half* __restrict__ Xh,
    const __half* __restrict__ Wtf, __half* __restrict__ H) {
    const int KC = K / 32;
    const int CTC = (K == 128) ? 8 : 16;
    const int NCHUNK = 16 / CTC;
    int t = threadIdx.x;
    int w = t >> 6, lane = t & 63;
    int m = lane & 15, quad = lane >> 4;
    int n0 = bid * 64;
    int nr = n0 + w * 16 + m;
    int nc = (nr < N_NODES) ? nr : (N_NODES - 1);

    half8 afrag[KC];
#pragma unroll
    for (int kc = 0; kc < KC; kc++)
        afrag[kc] = *(const half8*)(Xh + (size_t)nc * K + kc * 32 + quad * 8);

    floatx4 accs[16];
    const uint4* Wg = (const uint4*)Wtf;
#pragma unroll
    for (int c = 0; c < NCHUNK; c++) {
        __syncthreads();
        uint4* dstl = (uint4*)lds;
        const uint4* srcg = Wg + (size_t)c * 2048;
#pragma unroll
        for (int q = 0; q < 8; q++) dstl[t + 256 * q] = srcg[t + 256 * q];
        __syncthreads();
#pragma unroll
        for (int ctl = 0; ctl < CTC; ctl++) {
            floatx4 acc = {0.f, 0.f, 0.f, 0.f};
#pragma unroll
            for (int kc = 0; kc < KC; kc++) {
                half8 b = *(const half8*)&lds[((ctl * KC + kc) * 64 + lane) * 8];
                acc = __builtin_amdgcn_mfma_f32_16x16x32_f16(afrag[kc], b, acc, 0, 0, 0);
            }
            accs[c * CTC + ctl] = acc;
        }
    }
    __syncthreads();
    _Float16* myl = lds + w * (16 * 264);
#pragma unroll
    for (int ct = 0; ct < 16; ct++) {
        int cc = ct * 16 + m;            // GEMM col = h*64 + d
        int h = cc >> 6, d = cc & 63;
        int pos = d * 4 + h;             // H dim-major position
        int q = pos >> 6, o = pos & 63;  // padded quarter q at q*66
#pragma unroll
        for (int i = 0; i < 4; i++)
            myl[(quad * 4 + i) * 264 + q * 66 + o] = (_Float16)accs[ct][i];
    }
    __syncthreads();
    int r = t >> 2, p = t & 3;
    int n2 = n0 + r;
    if (n2 < N_NODES) {
        const _Float16* src = lds + (r >> 4) * (16 * 264) + (r & 15) * 264 + p * 66;
        uint4* dst = (uint4*)(H + (size_t)n2 * 256 + p * 64);
#pragma unroll
        for (int j = 0; j < 8; j++) dst[j] = ((const uint4*)src)[j];
    }
}

// ---------------- CSR build ----------------

// Merged: count_edges (blocks 0..NB_EDGE-1) + cast_al (rest). Independent:
// both depend only on prep. No LDS in either branch (the r23 fill+gemm
// merge failed precisely because static LDS poisons the latency-bound
// branch's occupancy — never merge LDS-heavy with latency-bound).
__global__ void __launch_bounds__(256) count_cast(
    const int* __restrict__ ei, int* __restrict__ counts,
    const int* __restrict__ flag, const float* __restrict__ X,
    const float* __restrict__ Wa0, __half* __restrict__ Xh,
    float* __restrict__ AL) {
    if (blockIdx.x < NB_EDGE) {
        int t = blockIdx.x * 256 + threadIdx.x;
        if (t >= E_TOT) return;
        int sh = flag[0] ? 0 : 1;             // int32 -> 0, int64 -> 1
        int dst = (t < E_RAW) ? ei[(E_RAW + t) << sh] : (t - E_RAW);
        atomicAdd(&counts[dst], 1);
    } else {
        int n = (blockIdx.x - NB_EDGE) * 256 + threadIdx.x;
        cast_al_body(n, X, Wa0, Xh, AL);
    }
}

__global__ void scan1(const int* __restrict__ counts, int* __restrict__ indptr,
                      int* __restrict__ bsums) {
    __shared__ int sd[256];
    int t = threadIdx.x;
    int i = blockIdx.x * 256 + t;
    int v = (i < N_NODES) ? counts[i] : 0;
    sd[t] = v;
    __syncthreads();
    for (int o = 1; o < 256; o <<= 1) {
        int x = (t >= o) ? sd[t - o] : 0;
        __syncthreads();
        sd[t] += x;
        __syncthreads();
    }
    int incl = sd[t];
    if (i < N_NODES) indptr[i] = incl - v;   // block-local exclusive
    if (t == 255) bsums[blockIdx.x] = incl;  // block total
}

// scan3 absorbs scan2: each block re-scans the 196 block sums.
__global__ void scan3(int* __restrict__ indptr, const int* __restrict__ bsums,
                      int* __restrict__ cursor) {
    __shared__ int sd[256];
    int t = threadIdx.x;
    int v = (t < NB_SCAN) ? bsums[t] : 0;
    sd[t] = v;
    __syncthreads();
    for (int o = 1; o < 256; o <<= 1) {
        int x = (t >= o) ? sd[t - o] : 0;
        __syncthreads();
        sd[t] += x;
        __syncthreads();
    }
    int off = (blockIdx.x == 0) ? 0 : sd[blockIdx.x - 1];  // exclusive prefix
    int i = blockIdx.x * 256 + t;
    if (i < N_NODES) {
        int val = indptr[i] + off;
        indptr[i] = val;
        cursor[i] = val;
    }
    if (i == 0) indptr[N_NODES] = E_TOT;
}

__global__ void fill_edges(const int* __restrict__ ei, int* __restrict__ cursor,
                           int* __restrict__ esrc, int* __restrict__ edst,
                           const int* __restrict__ flag) {
    int t = blockIdx.x * 256 + threadIdx.x;
    if (t >= E_TOT) return;
    int sh = flag[0] ? 0 : 1;
    int src, dst;
    if (t < E_RAW) { src = ei[t << sh]; dst = ei[(E_RAW + t) << sh]; }
    else           { src = t - E_RAW; dst = src; }
    int pos = atomicAdd(&cursor[dst], 1);
    esrc[pos] = src;
    edst[pos] = dst;
}

// ---------------- Merged compute launches ----------------
// gemm_h<128> (blocks 0..781) + edge_weights L0 (rest). Independent; EW
// tolerates the shared 33 KB LDS (bandwidth-bound, streaming).
__global__ void __launch_bounds__(256) gemm128_ew(
    const __half* __restrict__ Xh, const __half* __restrict__ Wtf,
    __half* __restrict__ H, const float* __restrict__ AL,
    const int* __restrict__ esrc, const int* __restrict__ edst,
    float4* __restrict__ EW) {
    __shared__ _Float16 lds[4 * 16 * 264];   // 33 KB (gemm branch only)
    if (blockIdx.x < NB_GEMH) {
        gemm_h_body<128>(blockIdx.x, lds, Xh, Wtf, H);
    } else {
        int p = (blockIdx.x - NB_GEMH) * 256 + threadIdx.x;
        ew_body(p, AL, esrc, edst, EW);
    }
}

// al_gemm64 (blocks 0..195) + gemm_h<64> (rest). Independent: both depend
// only on the preceding aggregate (al reads XA f32, gemm reads XA16 fp16).
__global__ void __launch_bounds__(256) al64_gemm64(
    const float* __restrict__ X, const float* __restrict__ Wa,
    float* __restrict__ ALout, const __half* __restrict__ Xh16,
    const __half* __restrict__ Wtf, __half* __restrict__ H) {
    __shared__ _Float16 lds[4 * 16 * 264];
    if (blockIdx.x < NB_SCAN) {
        int n = blockIdx.x * 256 + threadIdx.x;
        al64_body(n, X, Wa, ALout);
    } else {
        gemm_h_body<64>(blockIdx.x - NB_SCAN, lds, Xh16, Wtf, H);
    }
}

// standalone edge_weights (layers 1,2 — depends on al64 output)
__global__ void __launch_bounds__(256) edge_weights(
    const float* __restrict__ AL, const int* __restrict__ esrc,
    const int* __restrict__ edst, float4* __restrict__ EW) {
    int p = blockIdx.x * 256 + threadIdx.x;
    ew_body(p, AL, esrc, edst, EW);
}

// ---------------- Per-destination aggregation ----------------
// r14's bare body (68.2-70.0 us across 8 sessions; ~27% over the L2-miss
// fetch-path floor; every perturbation tried regressed — leave alone).
__global__ void __launch_bounds__(256) aggregate(
    const __half* __restrict__ H, const float4* __restrict__ EW,
    const int* __restrict__ indptr, const int* __restrict__ esrc,
    const float* __restrict__ bias, float* __restrict__ XOUT,
    __half* __restrict__ XOUT16) {
    int wave = threadIdx.x >> 6, lane = threadIdx.x & 63;
    int n = blockIdx.x * 4 + wave;   // 12500 * 4 == 50000 exactly

    int start = indptr[n], end = indptr[n + 1];
    const float2* H2 = (const float2*)H;    // 64 float2 per node row

    float d0 = 0.f, d1 = 0.f, d2 = 0.f, d3 = 0.f;
    float a0 = 0.f, a1 = 0.f, a2 = 0.f, a3 = 0.f;

#define EDGE_BODY(E, Hv)                                            \
    {                                                               \
        d0 += E.x; d1 += E.y; d2 += E.z; d3 += E.w;                 \
        float2 c01 = __half22float2(((const __half2*)&Hv)[0]);      \
        float2 c23 = __half22float2(((const __half2*)&Hv)[1]);      \
        a0 += E.x * c01.x; a1 += E.y * c01.y;                       \
        a2 += E.z * c23.x; a3 += E.w * c23.y;                       \
    }

    for (int cb = start; cb < end; cb += 64) {
        int cnt = end - cb; if (cnt > 64) cnt = 64;
        int my_s = (lane < cnt) ? esrc[cb + lane] : 0;
        for (int base = 0; base < cnt; base += 4) {
            int m = cnt - base;   // wave-uniform
            int r1 = (1 < m ? 1 : 0), r2 = (2 < m ? 2 : 0), r3 = (3 < m ? 3 : 0);
            int s0 = __shfl(my_s, base, 64);
            int s1 = __shfl(my_s, base + r1, 64);
            int s2 = __shfl(my_s, base + r2, 64);
            int s3 = __shfl(my_s, base + r3, 64);
            float4 E0 = EW[cb + base];                       // uniform -> bcast
            float4 E1 = EW[cb + base + r1];
            float4 E2 = EW[cb + base + r2];
            float4 E3 = EW[cb + base + r3];
            float2 H0 = H2[(s0 << 6) + lane];
            float2 H1 = H2[(s1 << 6) + lane];
            float2 H2v = H2[(s2 << 6) + lane];
            float2 H3 = H2[(s3 << 6) + lane];
            EDGE_BODY(E0, H0);
            if (m > 1) EDGE_BODY(E1, H1);
            if (m > 2) EDGE_BODY(E2, H2v);
            if (m > 3) EDGE_BODY(E3, H3);
        }
    }
#undef EDGE_BODY

    float r = a0 / d0 + a1 / d1 + a2 / d2 + a3 / d3;
    r = 0.25f * r + bias[lane];
    r = r > 0.f ? r : (__expf(r) - 1.f);   // ELU
    XOUT[n * 64 + lane] = r;
    if (XOUT16) XOUT16[n * 64 + lane] = __float2half(r);
}

// ---------------- Final FC ----------------
__global__ void __launch_bounds__(256) fc_kernel(
    const float* __restrict__ X, const float* __restrict__ fcW,
    const float* __restrict__ fcb, float* __restrict__ OUT) {
    __shared__ float ws[64 * 10];
    __shared__ float bs[10];
    int t = threadIdx.x;
    for (int i = t; i < 640; i += 256) ws[i] = fcW[i];   // 640 > blockDim
    if (t < 10) bs[t] = fcb[t];
    __syncthreads();
    int n = blockIdx.x * 256 + t;
    if (n >= N_NODES) return;
    float acc[10];
#pragma unroll
    for (int c = 0; c < 10; c++) acc[c] = bs[c];
    for (int d = 0; d < 64; d++) {
        float x = X[n * 64 + d];
#pragma unroll
        for (int c = 0; c < 10; c++) acc[c] += x * ws[d * 10 + c];
    }
#pragma unroll
    for (int c = 0; c < 10; c++) OUT[n * 10 + c] = acc[c];
}

// ---------------- Launch ----------------
extern "C" void kernel_launch(void* const* d_in, const int* in_sizes, int n_in,
                              void* d_out, int out_size, void* d_ws, size_t ws_size,
                              hipStream_t stream) {
    const float* x     = (const float*)d_in[0];
    const int*   ei    = (const int*)d_in[1];
    const float* W[3]    = {(const float*)d_in[2], (const float*)d_in[6], (const float*)d_in[10]};
    const float* asrc[3] = {(const float*)d_in[3], (const float*)d_in[7], (const float*)d_in[11]};
    const float* adst[3] = {(const float*)d_in[4], (const float*)d_in[8], (const float*)d_in[12]};
    const float* bias[3] = {(const float*)d_in[5], (const float*)d_in[9], (const float*)d_in[13]};
    const float* fcW = (const float*)d_in[14];
    const float* fcb = (const float*)d_in[15];
    float* out = (float*)d_out;

    char* ws = (char*)d_ws;
    size_t off = 0;
    auto alloc = [&](size_t bytes) {
        void* p = ws + off;
        off = (off + bytes + 255) & ~(size_t)255;
        return p;
    };
    __half* H     = (__half*)alloc((size_t)N_NODES * 256 * 2);  // 25.6 MB fp16
    float*  AL    = (float*)alloc((size_t)N_NODES * 8 * 4);     // 1.6 MB
    float4* EW    = (float4*)alloc((size_t)E_TOT * 16);         // 13.6 MB
    float*  XA    = (float*)alloc((size_t)N_NODES * 64 * 4);    // 12.8 MB
    float*  XB    = (float*)alloc((size_t)N_NODES * 64 * 4);    // 12.8 MB
    __half* Xh0   = (__half*)alloc((size_t)N_NODES * 128 * 2);  // 12.8 MB
    __half* XA16  = (__half*)alloc((size_t)N_NODES * 64 * 2);   // 6.4 MB
    __half* XB16  = (__half*)alloc((size_t)N_NODES * 64 * 2);   // 6.4 MB
    __half* Wtf0  = (__half*)alloc(4096 * 8 * 2);
    __half* Wtf1  = (__half*)alloc(2048 * 8 * 2);
    __half* Wtf2  = (__half*)alloc(2048 * 8 * 2);
    float*  Wa0   = (float*)alloc(128 * 8 * 4);
    float*  Wa1   = (float*)alloc(64 * 8 * 4);
    float*  Wa2   = (float*)alloc(64 * 8 * 4);
    int* counts = (int*)alloc((size_t)N_NODES * 4);
    int* indptr = (int*)alloc((size_t)(N_NODES + 1) * 4);
    int* cursor = (int*)alloc((size_t)N_NODES * 4);
    int* esrc   = (int*)alloc((size_t)E_TOT * 4);
    int* edst   = (int*)alloc((size_t)E_TOT * 4);
    int* bsums  = (int*)alloc(256 * 4);
    int* flag   = (int*)alloc(256 * 4);

    // Prep + CSR build (count_edges merged with cast_al — independent)
    prep_kernel<<<485, 256, 0, stream>>>(ei, counts, flag, W[0], W[1], W[2],
                                         Wtf0, Wtf1, Wtf2,
                                         asrc[0], adst[0], asrc[1], adst[1],
                                         asrc[2], adst[2], Wa0, Wa1, Wa2);
    count_cast<<<NB_EDGE + NB_SCAN, 256, 0, stream>>>(ei, counts, flag,
                                                      x, Wa0, Xh0, AL);
    scan1<<<NB_SCAN, 256, 0, stream>>>(counts, indptr, bsums);
    scan3<<<NB_SCAN, 256, 0, stream>>>(indptr, bsums, cursor);
    fill_edges<<<NB_EDGE, 256, 0, stream>>>(ei, cursor, esrc, edst, flag);

    // Layer 0 (gemm_h<128> merged with EW — independent)
    gemm128_ew<<<NB_GEMH + NB_EDGE, 256, 0, stream>>>(Xh0, Wtf0, H,
                                                      AL, esrc, edst, EW);
    aggregate<<<NB_NODE, 256, 0, stream>>>(H, EW, indptr, esrc, bias[0], XA, XA16);
    // Layer 1 (al_gemm64 merged with gemm_h<64>)
    al64_gemm64<<<NB_SCAN + NB_GEMH, 256, 0, stream>>>(XA, Wa1, AL,
                                                       XA16, Wtf1, H);
    edge_weights<<<NB_EDGE, 256, 0, stream>>>(AL, esrc, edst, EW);
    aggregate<<<NB_NODE, 256, 0, stream>>>(H, EW, indptr, esrc, bias[1], XB, XB16);
    // Layer 2
    al64_gemm64<<<NB_SCAN + NB_GEMH, 256, 0, stream>>>(XB, Wa2, AL,
                                                       XB16, Wtf2, H);
    edge_weights<<<NB_EDGE, 256, 0, stream>>>(AL, esrc, edst, EW);
    aggregate<<<NB_NODE, 256, 0, stream>>>(H, EW, indptr, esrc, bias[2], XA, nullptr);

    // Final FC
    fc_kernel<<<NB_SCAN, 256, 0, stream>>>(XA, fcW, fcb, out);
}